// Round 6
// baseline (850.320 us; speedup 1.0000x reference)
//
#include <hip/hip_runtime.h>
#include <math.h>

#define NN 4096
#define DIM 784
#define K62 62
#define CAP 128

// ---------------- squared row norms: f64 exact + f32 for keys ----------------
__global__ __launch_bounds__(256) void k_sqnorm(const float* __restrict__ x, double* __restrict__ sqnd,
                                                float* __restrict__ sqnf) {
    int r = blockIdx.x * 4 + (threadIdx.x >> 6);
    int lane = threadIdx.x & 63;
    const float* xr = x + (size_t)r * DIM;
    double s = 0.0;
    for (int k = lane; k < DIM; k += 64) { double v = (double)xr[k]; s += v * v; }
    for (int o = 32; o > 0; o >>= 1) s += __shfl_down(s, o);
    if (lane == 0) { sqnd[r] = s; sqnf[r] = (float)s; }
}

#define F4C(v, i) ((i) == 0 ? (v).x : (i) == 1 ? (v).y : (i) == 2 ? (v).z : (v).w)

// ---------------- standalone gram (R14-proven code; 17408 B LDS -> 8 blocks/CU) ----------------
__global__ __launch_bounds__(256, 4) void k_gram(const float* __restrict__ x, const float* __restrict__ sqnf,
                                                 float* __restrict__ Dm) {
    __shared__ __align__(16) unsigned char SB[17408];
    float* As = (float*)SB;            // [16][128] = 8192 B
    float* Bs = (float*)(SB + 8192);   // 16 rows x 140 words (swizzled) = 8960 B... overlaid by Cs later
    float* Cs = (float*)SB;            // 64*68 f = 17408 B (overlay, after K loops)
    int t = threadIdx.x;
    int id = blockIdx.x;
    int bi = (int)((sqrtf(8.f * (float)id + 1.f) - 1.f) * 0.5f);
    while ((bi + 1) * (bi + 2) / 2 <= id) ++bi;
    while (bi * (bi + 1) / 2 > id) --bi;
    int bj = id - bi * (bi + 1) / 2;
    int i0 = bi * 128, j0 = bj * 128;
    int tx = t & 15, ty = t >> 4;
    int lrow = t >> 1, lk = (t & 1) * 8;
    int wl = lrow + ((lrow >> 5) << 2);           // swizzled write word for col=lrow
    int bofs = tx * 8 + ((tx >> 2) << 2);         // swizzled read word for granule 2tx
    const float* arow = x + (size_t)(i0 + lrow) * DIM + lk;
    const float* brow = x + (size_t)(j0 + lrow) * DIM + lk;

    for (int pass = 0; pass < 2; ++pass) {
        float acc[4][8];
        #pragma unroll
        for (int r = 0; r < 4; ++r)
        #pragma unroll
        for (int c = 0; c < 8; ++c) acc[r][c] = 0.f;
        int abase = ty * 8 + pass * 4;
        for (int kk = 0; kk < DIM; kk += 16) {
            float4 a0 = *(const float4*)(arow + kk);
            float4 a1 = *(const float4*)(arow + kk + 4);
            float4 b0 = *(const float4*)(brow + kk);
            float4 b1 = *(const float4*)(brow + kk + 4);
            __syncthreads();
            As[(lk + 0) * 128 + lrow] = a0.x; As[(lk + 1) * 128 + lrow] = a0.y;
            As[(lk + 2) * 128 + lrow] = a0.z; As[(lk + 3) * 128 + lrow] = a0.w;
            As[(lk + 4) * 128 + lrow] = a1.x; As[(lk + 5) * 128 + lrow] = a1.y;
            As[(lk + 6) * 128 + lrow] = a1.z; As[(lk + 7) * 128 + lrow] = a1.w;
            Bs[(lk + 0) * 140 + wl] = b0.x; Bs[(lk + 1) * 140 + wl] = b0.y;
            Bs[(lk + 2) * 140 + wl] = b0.z; Bs[(lk + 3) * 140 + wl] = b0.w;
            Bs[(lk + 4) * 140 + wl] = b1.x; Bs[(lk + 5) * 140 + wl] = b1.y;
            Bs[(lk + 6) * 140 + wl] = b1.z; Bs[(lk + 7) * 140 + wl] = b1.w;
            __syncthreads();
            #pragma unroll
            for (int k = 0; k < 16; ++k) {
                float4 av  = *(const float4*)&As[k * 128 + abase];
                const float* bp = &Bs[k * 140 + bofs];
                float4 bv0 = *(const float4*)bp;
                float4 bv1 = *(const float4*)(bp + 4);
                float a[4]  = {av.x, av.y, av.z, av.w};
                float bb[8] = {bv0.x, bv0.y, bv0.z, bv0.w, bv1.x, bv1.y, bv1.z, bv1.w};
                #pragma unroll
                for (int r = 0; r < 4; ++r)
                #pragma unroll
                for (int c = 0; c < 8; ++c) acc[r][c] = fmaf(a[r], bb[c], acc[r][c]);
            }
        }
        float si[4], sj[8];
        #pragma unroll
        for (int r = 0; r < 4; ++r) si[r] = sqnf[i0 + abase + r];
        #pragma unroll
        for (int c = 0; c < 8; ++c) sj[c] = sqnf[j0 + tx * 8 + c];
        #pragma unroll
        for (int r = 0; r < 4; ++r)
        #pragma unroll
        for (int c = 0; c < 8; ++c) acc[r][c] = fmaxf(si[r] + sj[c] - 2.f * acc[r][c], 1e-12f);
        #pragma unroll
        for (int r = 0; r < 4; ++r) {
            size_t gi = (size_t)(i0 + abase + r) * NN + j0 + tx * 8;
            *(float4*)(Dm + gi)     = make_float4(acc[r][0], acc[r][1], acc[r][2], acc[r][3]);
            *(float4*)(Dm + gi + 4) = make_float4(acc[r][4], acc[r][5], acc[r][6], acc[r][7]);
        }
    }
    // mirror: read the just-written direct tile back (L2-hot), transpose via Cs, write coalesced.
    if (bi != bj) {
        for (int qr = 0; qr < 2; ++qr)
        for (int qc = 0; qc < 2; ++qc) {
            __syncthreads();
            #pragma unroll
            for (int g = 0; g < 4; ++g) {
                int idx = t + g * 256;
                int a = idx >> 4, f4i = idx & 15;
                float4 v = *(const float4*)&Dm[(size_t)(i0 + qr * 64 + a) * NN + j0 + qc * 64 + f4i * 4];
                Cs[(f4i * 4 + 0) * 68 + a] = v.x;
                Cs[(f4i * 4 + 1) * 68 + a] = v.y;
                Cs[(f4i * 4 + 2) * 68 + a] = v.z;
                Cs[(f4i * 4 + 3) * 68 + a] = v.w;
            }
            __syncthreads();
            #pragma unroll
            for (int g = 0; g < 4; ++g) {
                int idx = t + g * 256;
                int a = idx >> 4, f4j = idx & 15;
                float4 v = *(float4*)&Cs[a * 68 + f4j * 4];
                *(float4*)&Dm[(size_t)(j0 + qc * 64 + a) * NN + i0 + qr * 64 + f4j * 4] = v;
            }
        }
    }
}

// ---------------- fused encoder + topsel (R17) ----------------
// topsel depends only on Dm/sqnd/x (not the encoder); encoder depends only on x. They were
// serialized across dispatches. R15's lesson: fusion works only with SHORT, similar-scale block
// types (long gram blocks convoyed). Encoder blocks (~VALU-bound, 68% busy) and topsel blocks
// (memory-latency-bound, low VALU) are complementary: interleave 1:1 by bid parity so both
// populations co-reside across the whole dispatch; topsel's latency hides under encoder VALU.
__global__ __launch_bounds__(256, 4) void k_enctop(const float* __restrict__ x,
    const float* __restrict__ cw1, const float* __restrict__ cb1,
    const float* __restrict__ cw2, const float* __restrict__ cb2,
    const float* __restrict__ cw3, const float* __restrict__ cb3,
    const float* __restrict__ dw, const float* __restrict__ db,
    const float* __restrict__ Dm, const double* __restrict__ sqnd,
    double* __restrict__ Enc, double* __restrict__ esqd,
    double* __restrict__ topvd, int* __restrict__ topi)
{
    __shared__ __align__(16) unsigned char SB[22032];
    int t = threadIdx.x;
    int bid = blockIdx.x;

    if (bid & 1) {
        // ================= TOPSEL PATH (R16-proven binary-search threshold) =================
        float*    xi   = (float*)SB;               // 784 f = 3136 B
        unsigned* wsum = (unsigned*)(SB + 3136);   // 8 u
        int*      cj   = (int*)(SB + 3168);        // 128 i = 512 B
        double*   cvd  = (double*)(SB + 3680);     // 128 d = 1024 B
        unsigned* ncnt = (unsigned*)(SB + 4704);   // 1 u
        int i = bid >> 1;
        const float* drow = Dm + (size_t)i * NN;
        unsigned uk24[16];
        #pragma unroll
        for (int s = 0; s < 16; ++s) {
            int j = t + s * 256;
            unsigned u = __float_as_uint(drow[j]);
            uk24[s] = (j == i) ? 0u : (u >> 8);
        }
        for (int d = t; d < DIM; d += 256) xi[d] = x[(size_t)i * DIM + d];
        if (t == 0) ncnt[0] = 0;
        int lane = t & 63, w = t >> 6;
        unsigned lo = 0u, hi = 0x00FFFFFFu;
        for (int it = 0; it < 24; ++it) {
            unsigned mid = (lo + hi + 1u) >> 1;
            unsigned cnt = 0;
            #pragma unroll
            for (int s = 0; s < 16; ++s) cnt += (uk24[s] >= mid) ? 1u : 0u;
            #pragma unroll
            for (int off = 32; off > 0; off >>= 1) cnt += __shfl_down(cnt, off);
            if (lane == 0) wsum[(it & 1) * 4 + w] = cnt;
            __syncthreads();
            int bb = (it & 1) * 4;
            unsigned tot = wsum[bb] + wsum[bb + 1] + wsum[bb + 2] + wsum[bb + 3];
            if (tot >= 63u) lo = mid; else hi = mid - 1u;
        }
        unsigned prefix = lo;   // 24-bit prefix of the 63rd-largest key
        #pragma unroll
        for (int s = 0; s < 16; ++s) {
            if (uk24[s] >= prefix) {
                unsigned p = atomicAdd(ncnt, 1u);
                if (p < CAP) cj[p] = t + s * 256;
            }
        }
        __syncthreads();
        int ncand = min((int)ncnt[0], CAP);
        double sqi_d = sqnd[i];
        const float4* xi4 = (const float4*)xi;
        for (int c = w; c < ncand; c += 4) {
            const float4* xj4 = (const float4*)(x + (size_t)cj[c] * DIM);
            double s = 0.0;
            for (int k = lane; k < 196; k += 64) {
                float4 a = xi4[k]; float4 b = xj4[k];
                s = fma((double)a.x, (double)b.x, s);
                s = fma((double)a.y, (double)b.y, s);
                s = fma((double)a.z, (double)b.z, s);
                s = fma((double)a.w, (double)b.w, s);
            }
            for (int o = 32; o > 0; o >>= 1) s += __shfl_down(s, o);
            if (lane == 0) cvd[c] = sqrt(fmax(sqi_d + sqnd[cj[c]] - 2.0 * s, 1e-12));
        }
        __syncthreads();
        if (t < ncand) {
            double v = cvd[t]; int jj = cj[t];
            int r = 0;
            for (int c2 = 0; c2 < ncand; ++c2) {
                double v2 = cvd[c2];
                if (v2 > v || (v2 == v && cj[c2] < jj)) ++r;
            }
            if (r >= 1 && r < 63) {
                topvd[(size_t)i * K62 + r - 1] = v;
                topi[(size_t)i * K62 + r - 1] = jj;
            }
        }
        return;
    }

    // ================= ENCODER PATH (unchanged R14 code) =================
    float*  sb1  = (float*)(SB);             // 32 f
    float*  sb2  = (float*)(SB + 128);       // 32 f
    float*  sb3  = (float*)(SB + 256);       // 16 f
    float*  sdb  = (float*)(SB + 320);       // 16 f
    float*  scw1 = (float*)(SB + 384);       // 288 f  [384,1536)
    float*  wq   = (float*)(SB + 1536);      // 1152 f [1536,6144)
    float*  simg = (float*)(SB + 6144);      // 900 f  [6144,9744)
    float*  h1q  = (float*)(SB + 9744);      // 256 pos x 12 words = 3072 f [9744,22032)
    float*  wq3  = (float*)(SB + 1536);      // conv3 weights over wq
    float*  h2s  = (float*)(SB + 6144);      // 49 x 44 f = 8624 B over simg+h1q-head
    float*  c3   = (float*)(SB + 6144);      // 784 f over dead h2s head
    double* red  = (double*)(SB + 14768);    // 256 d [14768,16816)
    double* se   = (double*)(SB + 16816);    // 16 d

    int n = bid >> 1;
    for (int idx = t; idx < 3072; idx += 256) h1q[idx] = 0.f;
    for (int idx = t; idx < 900; idx += 256) simg[idx] = 0.f;
    __syncthreads();
    if (t < 196) {
        int row = t / 7, c4 = t % 7;
        float4 v = ((const float4*)(x + (size_t)n * DIM))[t];
        float* d = &simg[(row + 1) * 30 + 1 + c4 * 4];
        d[0] = v.x; d[1] = v.y; d[2] = v.z; d[3] = v.w;
    }
    for (int idx = t; idx < 288; idx += 256) scw1[idx] = cw1[idx];
    if (t < 32) { sb1[t] = cb1[t]; sb2[t] = cb2[t]; }
    if (t < 16) { sb3[t] = cb3[t]; sdb[t] = db[t]; }
    __syncthreads();

    int p2 = t >> 2, co8 = (t & 3) * 8;
    int py2 = p2 / 7, px2 = p2 % 7;
    float acc[4][8];   // [dy*2+dx][q]
    if (t < 196) {
        #pragma unroll
        for (int pp = 0; pp < 4; ++pp)
        #pragma unroll
        for (int q = 0; q < 8; ++q) acc[pp][q] = sb2[co8 + q];
    }

    for (int oct = 0; oct < 8; ++oct) {
        __syncthreads();
        for (int o = t; o < 784; o += 256) {
            int ch = o & 3, p = o >> 2;
            int py = p / 14, px = p % 14;
            int co = (oct << 2) + ch;
            float wv[9];
            #pragma unroll
            for (int tp = 0; tp < 9; ++tp) wv[tp] = scw1[tp * 32 + co];
            float bias = sb1[co];
            float m = 0.f;
            #pragma unroll
            for (int dy = 0; dy < 2; ++dy)
            #pragma unroll
            for (int dx = 0; dx < 2; ++dx) {
                const float* sp = &simg[(2 * py + dy + 1) * 30 + (2 * px + dx + 1)];
                float a = bias;
                a = fmaf(sp[-31], wv[0], a);
                a = fmaf(sp[-30], wv[1], a);
                a = fmaf(sp[-29], wv[2], a);
                a = fmaf(sp[ -1], wv[3], a);
                a = fmaf(sp[  0], wv[4], a);
                a = fmaf(sp[  1], wv[5], a);
                a = fmaf(sp[ 29], wv[6], a);
                a = fmaf(sp[ 30], wv[7], a);
                a = fmaf(sp[ 31], wv[8], a);
                if (a < 0.f) a = 0.f;
                if (a > m) m = a;
            }
            h1q[((py + 1) * 16 + (px + 1)) * 12 + ch] = m;
        }
        for (int w2 = t; w2 < 1152; w2 += 256) {
            int tap = w2 >> 7, k = w2 & 127;
            wq[w2] = cw2[tap * 1024 + oct * 128 + k];
        }
        __syncthreads();
        if (t < 196) {
            #pragma unroll
            for (int ky = 0; ky < 3; ++ky)
            #pragma unroll
            for (int kx = 0; kx < 3; ++kx) {
                const float* wb0 = &wq[(ky * 3 + kx) * 128 + co8];
                int rb = (2 * py2 + ky) * 16 + (2 * px2 + kx);
                float4 av00 = *(const float4*)&h1q[rb * 12];
                float4 av01 = *(const float4*)&h1q[(rb + 1) * 12];
                float4 av10 = *(const float4*)&h1q[(rb + 16) * 12];
                float4 av11 = *(const float4*)&h1q[(rb + 17) * 12];
                #pragma unroll
                for (int ci = 0; ci < 4; ++ci) {
                    float4 wA = *(const float4*)(wb0 + ci * 32);
                    float4 wB = *(const float4*)(wb0 + ci * 32 + 4);
                    float v00 = F4C(av00, ci), v01 = F4C(av01, ci);
                    float v10 = F4C(av10, ci), v11 = F4C(av11, ci);
                    acc[0][0] = fmaf(v00, wA.x, acc[0][0]); acc[0][1] = fmaf(v00, wA.y, acc[0][1]);
                    acc[0][2] = fmaf(v00, wA.z, acc[0][2]); acc[0][3] = fmaf(v00, wA.w, acc[0][3]);
                    acc[0][4] = fmaf(v00, wB.x, acc[0][4]); acc[0][5] = fmaf(v00, wB.y, acc[0][5]);
                    acc[0][6] = fmaf(v00, wB.z, acc[0][6]); acc[0][7] = fmaf(v00, wB.w, acc[0][7]);
                    acc[1][0] = fmaf(v01, wA.x, acc[1][0]); acc[1][1] = fmaf(v01, wA.y, acc[1][1]);
                    acc[1][2] = fmaf(v01, wA.z, acc[1][2]); acc[1][3] = fmaf(v01, wA.w, acc[1][3]);
                    acc[1][4] = fmaf(v01, wB.x, acc[1][4]); acc[1][5] = fmaf(v01, wB.y, acc[1][5]);
                    acc[1][6] = fmaf(v01, wB.z, acc[1][6]); acc[1][7] = fmaf(v01, wB.w, acc[1][7]);
                    acc[2][0] = fmaf(v10, wA.x, acc[2][0]); acc[2][1] = fmaf(v10, wA.y, acc[2][1]);
                    acc[2][2] = fmaf(v10, wA.z, acc[2][2]); acc[2][3] = fmaf(v10, wA.w, acc[2][3]);
                    acc[2][4] = fmaf(v10, wB.x, acc[2][4]); acc[2][5] = fmaf(v10, wB.y, acc[2][5]);
                    acc[2][6] = fmaf(v10, wB.z, acc[2][6]); acc[2][7] = fmaf(v10, wB.w, acc[2][7]);
                    acc[3][0] = fmaf(v11, wA.x, acc[3][0]); acc[3][1] = fmaf(v11, wA.y, acc[3][1]);
                    acc[3][2] = fmaf(v11, wA.z, acc[3][2]); acc[3][3] = fmaf(v11, wA.w, acc[3][3]);
                    acc[3][4] = fmaf(v11, wB.x, acc[3][4]); acc[3][5] = fmaf(v11, wB.y, acc[3][5]);
                    acc[3][6] = fmaf(v11, wB.z, acc[3][6]); acc[3][7] = fmaf(v11, wB.w, acc[3][7]);
                }
            }
        }
    }
    __syncthreads();
    if (t < 196) {
        float mm[8];
        #pragma unroll
        for (int q = 0; q < 8; ++q) {
            float m = 0.f;
            #pragma unroll
            for (int pp = 0; pp < 4; ++pp) {
                float a = acc[pp][q];
                if (a < 0.f) a = 0.f;
                if (a > m) m = a;
            }
            mm[q] = m;
        }
        *(float4*)&h2s[p2 * 44 + co8]     = make_float4(mm[0], mm[1], mm[2], mm[3]);
        *(float4*)&h2s[p2 * 44 + co8 + 4] = make_float4(mm[4], mm[5], mm[6], mm[7]);
    }
    float a0 = 0.f, a1 = 0.f, a2 = 0.f, a3 = 0.f;
    int p3 = t >> 2, co4 = (t & 3) * 4;
    int py3 = p3 / 7, px3 = p3 % 7;
    if (t < 196) {
        a0 = sb3[co4]; a1 = sb3[co4 + 1];
        a2 = sb3[co4 + 2]; a3 = sb3[co4 + 3];
    }
    for (int qq = 0; qq < 4; ++qq) {
        __syncthreads();
        for (int w2 = t; w2 < 1152; w2 += 256) {
            int tap = w2 >> 7, k = w2 & 127;
            wq3[w2] = cw3[tap * 512 + qq * 128 + k];
        }
        __syncthreads();
        if (t < 196) {
            for (int ky = 0; ky < 3; ++ky) {
                int iy = py3 + ky - 1; if ((unsigned)iy >= 7u) continue;
                for (int kx = 0; kx < 3; ++kx) {
                    int ix = px3 + kx - 1; if ((unsigned)ix >= 7u) continue;
                    const float* hp = &h2s[(iy * 7 + ix) * 44 + qq * 8];
                    float4 h0 = *(const float4*)hp;
                    float4 h1 = *(const float4*)(hp + 4);
                    const float* wp = &wq3[(ky * 3 + kx) * 128 + co4];
                    #pragma unroll
                    for (int ci = 0; ci < 8; ++ci) {
                        float av = (ci < 4) ? F4C(h0, ci) : F4C(h1, ci - 4);
                        float4 wv = *(const float4*)(wp + ci * 16);
                        a0 = fmaf(av, wv.x, a0); a1 = fmaf(av, wv.y, a1);
                        a2 = fmaf(av, wv.z, a2); a3 = fmaf(av, wv.w, a3);
                    }
                }
            }
        }
    }
    __syncthreads();
    if (t < 196) {
        float r0 = a0 > 0.f ? a0 : 0.f, r1 = a1 > 0.f ? a1 : 0.f;
        float r2 = a2 > 0.f ? a2 : 0.f, r3 = a3 > 0.f ? a3 : 0.f;
        *(float4*)&c3[p3 * 16 + co4] = make_float4(r0, r1, r2, r3);
    }
    __syncthreads();
    {
        int part = t >> 4, o = t & 15, j0 = part * 49;
        double s = 0.0;
        for (int j = 0; j < 49; ++j) s = fma((double)c3[j0 + j], (double)dw[(size_t)(j0 + j) * 16 + o], s);
        red[part * 16 + o] = s;
    }
    __syncthreads();
    if (t < 16) {
        double e = (double)sdb[t];
        for (int q = 0; q < 16; ++q) e += red[q * 16 + t];
        Enc[(size_t)n * 16 + t] = e;
        se[t] = e;
    }
    __syncthreads();
    if (t == 0) {
        double s = 0.0;
        for (int q = 0; q < 16; ++q) s += se[q] * se[q];
        esqd[n] = s;
    }
}

// ---------------- encoded distances + ratio partial (R17: no same-address atomics) ----------------
__global__ __launch_bounds__(256) void k_ratio(const double* __restrict__ Enc, const double* __restrict__ esqd,
                                               const double* __restrict__ topvd, const int* __restrict__ topi,
                                               double* __restrict__ vencd, double* __restrict__ Sp) {
    __shared__ double wp[4];
    int r = blockIdx.x * 4 + (threadIdx.x >> 6);
    int lane = threadIdx.x & 63, w = threadIdx.x >> 6;
    double ratio = 0.0;
    if (lane < K62) {
        int j = topi[(size_t)r * K62 + lane];
        const double* Er = Enc + (size_t)r * 16;
        const double* Ej = Enc + (size_t)j * 16;
        double dot = 0.0;
        #pragma unroll
        for (int q = 0; q < 16; ++q) dot = fma(Er[q], Ej[q], dot);
        double ve = sqrt(fmax(esqd[r] + esqd[j] - 2.0 * dot, 1e-12));
        vencd[(size_t)r * K62 + lane] = ve;
        ratio = topvd[(size_t)r * K62 + lane] / ve;
    }
    for (int o = 32; o > 0; o >>= 1) ratio += __shfl_down(ratio, o);
    if (lane == 0) wp[w] = ratio;
    __syncthreads();
    if (threadIdx.x == 0) Sp[blockIdx.x] = wp[0] + wp[1] + wp[2] + wp[3];
}

__global__ __launch_bounds__(256) void k_rsum(const double* __restrict__ Sp, double* __restrict__ Ssum) {
    __shared__ double wp[4];
    int t = threadIdx.x, lane = t & 63, w = t >> 6;
    double s = Sp[t] + Sp[t + 256] + Sp[t + 512] + Sp[t + 768];
    for (int o = 32; o > 0; o >>= 1) s += __shfl_down(s, o);
    if (lane == 0) wp[w] = s;
    __syncthreads();
    if (t == 0) Ssum[0] = wp[0] + wp[1] + wp[2] + wp[3];
}

// ---------------- final loss partials ----------------
__global__ __launch_bounds__(256) void k_loss(const double* __restrict__ topvd, const double* __restrict__ vencd,
                                              const double* __restrict__ Ssum, double* __restrict__ Lp) {
    __shared__ double wp[4];
    int r = blockIdx.x * 4 + (threadIdx.x >> 6);
    int lane = threadIdx.x & 63, w = threadIdx.x >> 6;
    double m = Ssum[0] * (1.0 / (4096.0 * 62.0));
    double v = -1.0;
    if (lane < K62) {
        double d = topvd[(size_t)r * K62 + lane] - m * vencd[(size_t)r * K62 + lane];
        v = d * d;
    }
    for (int o = 32; o > 0; o >>= 1) { double ov = __shfl_down(v, o); v = (ov > v) ? ov : v; }
    if (lane == 0) wp[w] = v;
    __syncthreads();
    if (threadIdx.x == 0) Lp[blockIdx.x] = wp[0] + wp[1] + wp[2] + wp[3];
}

__global__ __launch_bounds__(256) void k_final(const double* __restrict__ Lp, float* __restrict__ out) {
    __shared__ double wp[4];
    int t = threadIdx.x, lane = t & 63, w = t >> 6;
    double s = Lp[t] + Lp[t + 256] + Lp[t + 512] + Lp[t + 768];
    for (int o = 32; o > 0; o >>= 1) s += __shfl_down(s, o);
    if (lane == 0) wp[w] = s;
    __syncthreads();
    if (t == 0) out[0] = (float)((wp[0] + wp[1] + wp[2] + wp[3]) * (1.0 / 4096.0));
}

extern "C" void kernel_launch(void* const* d_in, const int* in_sizes, int n_in,
                              void* d_out, int out_size, void* d_ws, size_t ws_size,
                              hipStream_t stream) {
    const float* x   = (const float*)d_in[0];
    const float* cw1 = (const float*)d_in[1];
    const float* cb1 = (const float*)d_in[2];
    const float* cw2 = (const float*)d_in[3];
    const float* cb2 = (const float*)d_in[4];
    const float* cw3 = (const float*)d_in[5];
    const float* cb3 = (const float*)d_in[6];
    const float* dw  = (const float*)d_in[7];
    const float* db  = (const float*)d_in[8];

    float*  ws    = (float*)d_ws;
    float*  Dm    = ws;                          // 16,777,216 f = 64 MB
    double* Enc   = (double*)(ws + 16777216);    // 65,536 d
    double* esqd  = Enc + 65536;                 // 4,096 d
    double* sqnd  = esqd + 4096;                 // 4,096 d
    float*  sqnf  = (float*)(sqnd + 4096);       // 4,096 f
    double* topvd = (double*)(sqnf + 4096);      // 253,952 d
    double* vencd = topvd + 253952;              // 253,952 d
    double* Ssum  = vencd + 253952;              // 1 d
    double* Lsum  = Ssum + 1;                    // 1 d (unused, layout keep)
    int*    topi  = (int*)(Lsum + 1);            // 253,952 i
    double* Sp    = (double*)(topi + 253952);    // 1,024 d
    double* Lp    = Sp + 1024;                   // 1,024 d
    float*  out   = (float*)d_out;

    k_sqnorm<<<1024, 256, 0, stream>>>(x, sqnd, sqnf);
    k_gram<<<528, 256, 0, stream>>>(x, sqnf, Dm);
    k_enctop<<<8192, 256, 0, stream>>>(x, cw1, cb1, cw2, cb2, cw3, cb3, dw, db,
                                       Dm, sqnd, Enc, esqd, topvd, topi);
    k_ratio<<<1024, 256, 0, stream>>>(Enc, esqd, topvd, topi, vencd, Sp);
    k_rsum<<<1, 256, 0, stream>>>(Sp, Ssum);
    k_loss<<<1024, 256, 0, stream>>>(topvd, vencd, Ssum, Lp);
    k_final<<<1, 256, 0, stream>>>(Lp, out);
}

// Round 7
// 653.195 us; speedup vs baseline: 1.3018x; 1.3018x over previous
//
#include <hip/hip_runtime.h>
#include <math.h>

#define NN 4096
#define DIM 784
#define K62 62
#define CAP 128

// ---------------- squared row norms: f64 exact + f32 for keys ----------------
__global__ __launch_bounds__(256) void k_sqnorm(const float* __restrict__ x, double* __restrict__ sqnd,
                                                float* __restrict__ sqnf) {
    int r = blockIdx.x * 4 + (threadIdx.x >> 6);
    int lane = threadIdx.x & 63;
    const float* xr = x + (size_t)r * DIM;
    double s = 0.0;
    for (int k = lane; k < DIM; k += 64) { double v = (double)xr[k]; s += v * v; }
    for (int o = 32; o > 0; o >>= 1) s += __shfl_down(s, o);
    if (lane == 0) { sqnd[r] = s; sqnf[r] = (float)s; }
}

#define F4C(v, i) ((i) == 0 ? (v).x : (i) == 1 ? (v).y : (i) == 2 ? (v).z : (v).w)

// pack two f32 d^2 values into one uint of two 16-bit keys (upper 16 bits of the f32 pattern).
// Monotone for positive floats -> selection-equivalent. Dm stores KEYS ONLY; refine recomputes
// exact distances from x in f64, so final outputs are bit-identical to the f32-Dm version.
__device__ __forceinline__ unsigned pk16(float a, float b) {
    return (__float_as_uint(a) >> 16) | (__float_as_uint(b) & 0xFFFF0000u);
}

// ---------------- fused gram-head + encoder (R16-proven structure; Dm -> 16-bit keys) ----------------
// R17 post-mortem: heterogeneous same-kernel fusion failed twice (R15 convoy, R17 issue-slot
// interference: VALUBusy 68->53, enctop 593 > serial 545). Reverted to the proven serial shape:
// gram blocks 0..527 then encoder blocks. New in R18: Dm stored as ushort keys (topsel never
// reads Dm values - only selects by them), halving gram write traffic and topsel's 64 MB scan.
__global__ __launch_bounds__(256, 4) void k_encgram(const float* __restrict__ x,
    const float* __restrict__ cw1, const float* __restrict__ cb1,
    const float* __restrict__ cw2, const float* __restrict__ cb2,
    const float* __restrict__ cw3, const float* __restrict__ cb3,
    const float* __restrict__ dw, const float* __restrict__ db,
    const float* __restrict__ sqnf,
    unsigned short* __restrict__ Dm16, double* __restrict__ Enc, double* __restrict__ esqd)
{
    __shared__ __align__(16) unsigned char SB[22032];
    int t = threadIdx.x;

    if (blockIdx.x < 528) {
        // ================= GRAM PATH =================
        float* As = (float*)SB;            // [16][128] = 8192 B
        float* Bs = (float*)(SB + 8192);   // 16 rows x 140 words (swizzled) = 8960 B
        unsigned short* Cs16 = (unsigned short*)SB;  // 64 x 72 ushorts = 9216 B (overlay after K loops)
        int id = blockIdx.x;
        int bi = (int)((sqrtf(8.f * (float)id + 1.f) - 1.f) * 0.5f);
        while ((bi + 1) * (bi + 2) / 2 <= id) ++bi;
        while (bi * (bi + 1) / 2 > id) --bi;
        int bj = id - bi * (bi + 1) / 2;
        int i0 = bi * 128, j0 = bj * 128;
        int tx = t & 15, ty = t >> 4;
        int lrow = t >> 1, lk = (t & 1) * 8;
        int wl = lrow + ((lrow >> 5) << 2);           // swizzled write word for col=lrow
        int bofs = tx * 8 + ((tx >> 2) << 2);         // swizzled read word for granule 2tx
        const float* arow = x + (size_t)(i0 + lrow) * DIM + lk;
        const float* brow = x + (size_t)(j0 + lrow) * DIM + lk;

        for (int pass = 0; pass < 2; ++pass) {
            float acc[4][8];
            #pragma unroll
            for (int r = 0; r < 4; ++r)
            #pragma unroll
            for (int c = 0; c < 8; ++c) acc[r][c] = 0.f;
            int abase = ty * 8 + pass * 4;
            for (int kk = 0; kk < DIM; kk += 16) {
                float4 a0 = *(const float4*)(arow + kk);
                float4 a1 = *(const float4*)(arow + kk + 4);
                float4 b0 = *(const float4*)(brow + kk);
                float4 b1 = *(const float4*)(brow + kk + 4);
                __syncthreads();
                As[(lk + 0) * 128 + lrow] = a0.x; As[(lk + 1) * 128 + lrow] = a0.y;
                As[(lk + 2) * 128 + lrow] = a0.z; As[(lk + 3) * 128 + lrow] = a0.w;
                As[(lk + 4) * 128 + lrow] = a1.x; As[(lk + 5) * 128 + lrow] = a1.y;
                As[(lk + 6) * 128 + lrow] = a1.z; As[(lk + 7) * 128 + lrow] = a1.w;
                Bs[(lk + 0) * 140 + wl] = b0.x; Bs[(lk + 1) * 140 + wl] = b0.y;
                Bs[(lk + 2) * 140 + wl] = b0.z; Bs[(lk + 3) * 140 + wl] = b0.w;
                Bs[(lk + 4) * 140 + wl] = b1.x; Bs[(lk + 5) * 140 + wl] = b1.y;
                Bs[(lk + 6) * 140 + wl] = b1.z; Bs[(lk + 7) * 140 + wl] = b1.w;
                __syncthreads();
                #pragma unroll
                for (int k = 0; k < 16; ++k) {
                    float4 av  = *(const float4*)&As[k * 128 + abase];
                    const float* bp = &Bs[k * 140 + bofs];
                    float4 bv0 = *(const float4*)bp;
                    float4 bv1 = *(const float4*)(bp + 4);
                    float a[4]  = {av.x, av.y, av.z, av.w};
                    float bb[8] = {bv0.x, bv0.y, bv0.z, bv0.w, bv1.x, bv1.y, bv1.z, bv1.w};
                    #pragma unroll
                    for (int r = 0; r < 4; ++r)
                    #pragma unroll
                    for (int c = 0; c < 8; ++c) acc[r][c] = fmaf(a[r], bb[c], acc[r][c]);
                }
            }
            float si[4], sj[8];
            #pragma unroll
            for (int r = 0; r < 4; ++r) si[r] = sqnf[i0 + abase + r];
            #pragma unroll
            for (int c = 0; c < 8; ++c) sj[c] = sqnf[j0 + tx * 8 + c];
            #pragma unroll
            for (int r = 0; r < 4; ++r) {
                #pragma unroll
                for (int c = 0; c < 8; ++c) acc[r][c] = fmaxf(si[r] + sj[c] - 2.f * acc[r][c], 1e-12f);
                uint4 u;
                u.x = pk16(acc[r][0], acc[r][1]);
                u.y = pk16(acc[r][2], acc[r][3]);
                u.z = pk16(acc[r][4], acc[r][5]);
                u.w = pk16(acc[r][6], acc[r][7]);
                *(uint4*)(Dm16 + (size_t)(i0 + abase + r) * NN + j0 + tx * 8) = u;
            }
        }
        // mirror: read the just-written ushort tile back (L2-hot), transpose via Cs16, write coalesced.
        if (bi != bj) {
            for (int qr = 0; qr < 2; ++qr)
            for (int qc = 0; qc < 2; ++qc) {
                __syncthreads();
                #pragma unroll
                for (int g = 0; g < 2; ++g) {
                    int idx = t + g * 256;            // 512 items: 64 rows x 8 uint4-chunks
                    int a = idx >> 3, c8 = idx & 7;
                    uint4 v = *(const uint4*)&Dm16[(size_t)(i0 + qr * 64 + a) * NN + j0 + qc * 64 + c8 * 8];
                    Cs16[(c8 * 8 + 0) * 72 + a] = (unsigned short)(v.x);
                    Cs16[(c8 * 8 + 1) * 72 + a] = (unsigned short)(v.x >> 16);
                    Cs16[(c8 * 8 + 2) * 72 + a] = (unsigned short)(v.y);
                    Cs16[(c8 * 8 + 3) * 72 + a] = (unsigned short)(v.y >> 16);
                    Cs16[(c8 * 8 + 4) * 72 + a] = (unsigned short)(v.z);
                    Cs16[(c8 * 8 + 5) * 72 + a] = (unsigned short)(v.z >> 16);
                    Cs16[(c8 * 8 + 6) * 72 + a] = (unsigned short)(v.w);
                    Cs16[(c8 * 8 + 7) * 72 + a] = (unsigned short)(v.w >> 16);
                }
                __syncthreads();
                #pragma unroll
                for (int g = 0; g < 2; ++g) {
                    int idx = t + g * 256;
                    int a = idx >> 3, c8 = idx & 7;
                    uint4 v = *(const uint4*)&Cs16[a * 72 + c8 * 8];
                    *(uint4*)&Dm16[(size_t)(j0 + qc * 64 + a) * NN + i0 + qr * 64 + c8 * 8] = v;
                }
            }
        }
        return;
    }

    // ================= ENCODER PATH (unchanged R14/R16 code) =================
    float*  sb1  = (float*)(SB);             // 32 f
    float*  sb2  = (float*)(SB + 128);       // 32 f
    float*  sb3  = (float*)(SB + 256);       // 16 f
    float*  sdb  = (float*)(SB + 320);       // 16 f
    float*  scw1 = (float*)(SB + 384);       // 288 f  [384,1536)
    float*  wq   = (float*)(SB + 1536);      // 1152 f [1536,6144)
    float*  simg = (float*)(SB + 6144);      // 900 f  [6144,9744)
    float*  h1q  = (float*)(SB + 9744);      // 256 pos x 12 words = 3072 f [9744,22032)
    float*  wq3  = (float*)(SB + 1536);      // conv3 weights over wq
    float*  h2s  = (float*)(SB + 6144);      // 49 x 44 f = 8624 B over simg+h1q-head
    float*  c3   = (float*)(SB + 6144);      // 784 f over dead h2s head
    double* red  = (double*)(SB + 14768);    // 256 d [14768,16816)
    double* se   = (double*)(SB + 16816);    // 16 d

    int n = blockIdx.x - 528;
    for (int idx = t; idx < 3072; idx += 256) h1q[idx] = 0.f;
    for (int idx = t; idx < 900; idx += 256) simg[idx] = 0.f;
    __syncthreads();
    if (t < 196) {
        int row = t / 7, c4 = t % 7;
        float4 v = ((const float4*)(x + (size_t)n * DIM))[t];
        float* d = &simg[(row + 1) * 30 + 1 + c4 * 4];
        d[0] = v.x; d[1] = v.y; d[2] = v.z; d[3] = v.w;
    }
    for (int idx = t; idx < 288; idx += 256) scw1[idx] = cw1[idx];
    if (t < 32) { sb1[t] = cb1[t]; sb2[t] = cb2[t]; }
    if (t < 16) { sb3[t] = cb3[t]; sdb[t] = db[t]; }
    __syncthreads();

    int p2 = t >> 2, co8 = (t & 3) * 8;
    int py2 = p2 / 7, px2 = p2 % 7;
    float acc[4][8];   // [dy*2+dx][q]
    if (t < 196) {
        #pragma unroll
        for (int pp = 0; pp < 4; ++pp)
        #pragma unroll
        for (int q = 0; q < 8; ++q) acc[pp][q] = sb2[co8 + q];
    }

    for (int oct = 0; oct < 8; ++oct) {
        __syncthreads();
        for (int o = t; o < 784; o += 256) {
            int ch = o & 3, p = o >> 2;
            int py = p / 14, px = p % 14;
            int co = (oct << 2) + ch;
            float wv[9];
            #pragma unroll
            for (int tp = 0; tp < 9; ++tp) wv[tp] = scw1[tp * 32 + co];
            float bias = sb1[co];
            float m = 0.f;
            #pragma unroll
            for (int dy = 0; dy < 2; ++dy)
            #pragma unroll
            for (int dx = 0; dx < 2; ++dx) {
                const float* sp = &simg[(2 * py + dy + 1) * 30 + (2 * px + dx + 1)];
                float a = bias;
                a = fmaf(sp[-31], wv[0], a);
                a = fmaf(sp[-30], wv[1], a);
                a = fmaf(sp[-29], wv[2], a);
                a = fmaf(sp[ -1], wv[3], a);
                a = fmaf(sp[  0], wv[4], a);
                a = fmaf(sp[  1], wv[5], a);
                a = fmaf(sp[ 29], wv[6], a);
                a = fmaf(sp[ 30], wv[7], a);
                a = fmaf(sp[ 31], wv[8], a);
                if (a < 0.f) a = 0.f;
                if (a > m) m = a;
            }
            h1q[((py + 1) * 16 + (px + 1)) * 12 + ch] = m;
        }
        for (int w2 = t; w2 < 1152; w2 += 256) {
            int tap = w2 >> 7, k = w2 & 127;
            wq[w2] = cw2[tap * 1024 + oct * 128 + k];
        }
        __syncthreads();
        if (t < 196) {
            #pragma unroll
            for (int ky = 0; ky < 3; ++ky)
            #pragma unroll
            for (int kx = 0; kx < 3; ++kx) {
                const float* wb0 = &wq[(ky * 3 + kx) * 128 + co8];
                int rb = (2 * py2 + ky) * 16 + (2 * px2 + kx);
                float4 av00 = *(const float4*)&h1q[rb * 12];
                float4 av01 = *(const float4*)&h1q[(rb + 1) * 12];
                float4 av10 = *(const float4*)&h1q[(rb + 16) * 12];
                float4 av11 = *(const float4*)&h1q[(rb + 17) * 12];
                #pragma unroll
                for (int ci = 0; ci < 4; ++ci) {
                    float4 wA = *(const float4*)(wb0 + ci * 32);
                    float4 wB = *(const float4*)(wb0 + ci * 32 + 4);
                    float v00 = F4C(av00, ci), v01 = F4C(av01, ci);
                    float v10 = F4C(av10, ci), v11 = F4C(av11, ci);
                    acc[0][0] = fmaf(v00, wA.x, acc[0][0]); acc[0][1] = fmaf(v00, wA.y, acc[0][1]);
                    acc[0][2] = fmaf(v00, wA.z, acc[0][2]); acc[0][3] = fmaf(v00, wA.w, acc[0][3]);
                    acc[0][4] = fmaf(v00, wB.x, acc[0][4]); acc[0][5] = fmaf(v00, wB.y, acc[0][5]);
                    acc[0][6] = fmaf(v00, wB.z, acc[0][6]); acc[0][7] = fmaf(v00, wB.w, acc[0][7]);
                    acc[1][0] = fmaf(v01, wA.x, acc[1][0]); acc[1][1] = fmaf(v01, wA.y, acc[1][1]);
                    acc[1][2] = fmaf(v01, wA.z, acc[1][2]); acc[1][3] = fmaf(v01, wA.w, acc[1][3]);
                    acc[1][4] = fmaf(v01, wB.x, acc[1][4]); acc[1][5] = fmaf(v01, wB.y, acc[1][5]);
                    acc[1][6] = fmaf(v01, wB.z, acc[1][6]); acc[1][7] = fmaf(v01, wB.w, acc[1][7]);
                    acc[2][0] = fmaf(v10, wA.x, acc[2][0]); acc[2][1] = fmaf(v10, wA.y, acc[2][1]);
                    acc[2][2] = fmaf(v10, wA.z, acc[2][2]); acc[2][3] = fmaf(v10, wA.w, acc[2][3]);
                    acc[2][4] = fmaf(v10, wB.x, acc[2][4]); acc[2][5] = fmaf(v10, wB.y, acc[2][5]);
                    acc[2][6] = fmaf(v10, wB.z, acc[2][6]); acc[2][7] = fmaf(v10, wB.w, acc[2][7]);
                    acc[3][0] = fmaf(v11, wA.x, acc[3][0]); acc[3][1] = fmaf(v11, wA.y, acc[3][1]);
                    acc[3][2] = fmaf(v11, wA.z, acc[3][2]); acc[3][3] = fmaf(v11, wA.w, acc[3][3]);
                    acc[3][4] = fmaf(v11, wB.x, acc[3][4]); acc[3][5] = fmaf(v11, wB.y, acc[3][5]);
                    acc[3][6] = fmaf(v11, wB.z, acc[3][6]); acc[3][7] = fmaf(v11, wB.w, acc[3][7]);
                }
            }
        }
    }
    __syncthreads();
    if (t < 196) {
        float mm[8];
        #pragma unroll
        for (int q = 0; q < 8; ++q) {
            float m = 0.f;
            #pragma unroll
            for (int pp = 0; pp < 4; ++pp) {
                float a = acc[pp][q];
                if (a < 0.f) a = 0.f;
                if (a > m) m = a;
            }
            mm[q] = m;
        }
        *(float4*)&h2s[p2 * 44 + co8]     = make_float4(mm[0], mm[1], mm[2], mm[3]);
        *(float4*)&h2s[p2 * 44 + co8 + 4] = make_float4(mm[4], mm[5], mm[6], mm[7]);
    }
    float a0 = 0.f, a1 = 0.f, a2 = 0.f, a3 = 0.f;
    int p3 = t >> 2, co4 = (t & 3) * 4;
    int py3 = p3 / 7, px3 = p3 % 7;
    if (t < 196) {
        a0 = sb3[co4]; a1 = sb3[co4 + 1];
        a2 = sb3[co4 + 2]; a3 = sb3[co4 + 3];
    }
    for (int qq = 0; qq < 4; ++qq) {
        __syncthreads();
        for (int w2 = t; w2 < 1152; w2 += 256) {
            int tap = w2 >> 7, k = w2 & 127;
            wq3[w2] = cw3[tap * 512 + qq * 128 + k];
        }
        __syncthreads();
        if (t < 196) {
            for (int ky = 0; ky < 3; ++ky) {
                int iy = py3 + ky - 1; if ((unsigned)iy >= 7u) continue;
                for (int kx = 0; kx < 3; ++kx) {
                    int ix = px3 + kx - 1; if ((unsigned)ix >= 7u) continue;
                    const float* hp = &h2s[(iy * 7 + ix) * 44 + qq * 8];
                    float4 h0 = *(const float4*)hp;
                    float4 h1 = *(const float4*)(hp + 4);
                    const float* wp = &wq3[(ky * 3 + kx) * 128 + co4];
                    #pragma unroll
                    for (int ci = 0; ci < 8; ++ci) {
                        float av = (ci < 4) ? F4C(h0, ci) : F4C(h1, ci - 4);
                        float4 wv = *(const float4*)(wp + ci * 16);
                        a0 = fmaf(av, wv.x, a0); a1 = fmaf(av, wv.y, a1);
                        a2 = fmaf(av, wv.z, a2); a3 = fmaf(av, wv.w, a3);
                    }
                }
            }
        }
    }
    __syncthreads();
    if (t < 196) {
        float r0 = a0 > 0.f ? a0 : 0.f, r1 = a1 > 0.f ? a1 : 0.f;
        float r2 = a2 > 0.f ? a2 : 0.f, r3 = a3 > 0.f ? a3 : 0.f;
        *(float4*)&c3[p3 * 16 + co4] = make_float4(r0, r1, r2, r3);
    }
    __syncthreads();
    {
        int part = t >> 4, o = t & 15, j0 = part * 49;
        double s = 0.0;
        for (int j = 0; j < 49; ++j) s = fma((double)c3[j0 + j], (double)dw[(size_t)(j0 + j) * 16 + o], s);
        red[part * 16 + o] = s;
    }
    __syncthreads();
    if (t < 16) {
        double e = (double)sdb[t];
        for (int q = 0; q < 16; ++q) e += red[q * 16 + t];
        Enc[(size_t)n * 16 + t] = e;
        se[t] = e;
    }
    __syncthreads();
    if (t == 0) {
        double s = 0.0;
        for (int q = 0; q < 16; ++q) s += se[q] * se[q];
        esqd[n] = s;
    }
}

// ---------------- selection (R18): 16-bit key scan + 16-lane-group refine ----------------
// Keys are the upper 16 bits of the f32 d^2 pattern (monotone). Binary search finds the key of
// the 63rd-largest; candidate set = {key >= it} is a superset of the true top-63 (ties widen it
// by ~14 for this data; CAP=128 ample). Exact f64 refine + rank make outputs bit-identical.
// Refine uses 16-lane groups: 16 candidate gathers in flight per block (was 4) to hide the
// ~500-900 cy HBM/L3 gather latency that dominated (topsel FETCH ~200 MB, R17 measured).
__global__ __launch_bounds__(256) void k_topsel(const unsigned short* __restrict__ Dm16,
                                                const double* __restrict__ sqnd,
                                                const float* __restrict__ x,
                                                double* __restrict__ topvd, int* __restrict__ topi) {
    __shared__ float xi[DIM];
    __shared__ unsigned wsum[8];
    __shared__ int cj[CAP];
    __shared__ double cvd[CAP];
    __shared__ unsigned ncnt;
    int i = blockIdx.x, t = threadIdx.x;
    const unsigned* drow = (const unsigned*)(Dm16 + (size_t)i * NN);   // 2048 uints = 4096 keys
    unsigned uk[8];
    #pragma unroll
    for (int s = 0; s < 8; ++s) {
        int wd = t + s * 256;
        unsigned u = drow[wd];
        if (2 * wd == i)     u &= 0xFFFF0000u;   // mask self (low key)
        if (2 * wd + 1 == i) u &= 0x0000FFFFu;   // mask self (high key)
        uk[s] = u;
    }
    if (t < 196) ((float4*)xi)[t] = ((const float4*)(x + (size_t)i * DIM))[t];
    if (t == 0) ncnt = 0;
    int lane = t & 63, w = t >> 6;
    unsigned lo = 0u, hi = 0xFFFFu;
    for (int it = 0; it < 16; ++it) {
        unsigned mid = (lo + hi + 1u) >> 1;
        unsigned cnt = 0;
        #pragma unroll
        for (int s = 0; s < 8; ++s) {
            cnt += ((uk[s] & 0xFFFFu) >= mid) ? 1u : 0u;
            cnt += ((uk[s] >> 16) >= mid) ? 1u : 0u;
        }
        #pragma unroll
        for (int off = 32; off > 0; off >>= 1) cnt += __shfl_down(cnt, off);
        if (lane == 0) wsum[(it & 1) * 4 + w] = cnt;
        __syncthreads();
        int bb = (it & 1) * 4;
        unsigned tot = wsum[bb] + wsum[bb + 1] + wsum[bb + 2] + wsum[bb + 3];
        if (tot >= 63u) lo = mid; else hi = mid - 1u;
    }
    unsigned prefix = lo;   // 16-bit key of the 63rd-largest distance
    #pragma unroll
    for (int s = 0; s < 8; ++s) {
        int wd = t + s * 256;
        if ((uk[s] & 0xFFFFu) >= prefix) {
            unsigned p = atomicAdd(&ncnt, 1u);
            if (p < CAP) cj[p] = 2 * wd;
        }
        if ((uk[s] >> 16) >= prefix) {
            unsigned p = atomicAdd(&ncnt, 1u);
            if (p < CAP) cj[p] = 2 * wd + 1;
        }
    }
    __syncthreads();
    int ncand = min((int)ncnt, CAP);
    double sqi_d = sqnd[i];
    const float4* xi4 = (const float4*)xi;
    int g = t >> 4, gl = t & 15;   // 16 groups of 16 lanes: 16 gathers in flight
    for (int c = g; c < ncand; c += 16) {
        const float4* xj4 = (const float4*)(x + (size_t)cj[c] * DIM);
        double s = 0.0;
        for (int k = gl; k < 196; k += 16) {
            float4 a = xi4[k]; float4 b = xj4[k];
            s = fma((double)a.x, (double)b.x, s);
            s = fma((double)a.y, (double)b.y, s);
            s = fma((double)a.z, (double)b.z, s);
            s = fma((double)a.w, (double)b.w, s);
        }
        #pragma unroll
        for (int o = 8; o > 0; o >>= 1) s += __shfl_down(s, o, 16);
        if (gl == 0) cvd[c] = sqrt(fmax(sqi_d + sqnd[cj[c]] - 2.0 * s, 1e-12));
    }
    __syncthreads();
    if (t < ncand) {
        double v = cvd[t]; int jj = cj[t];
        int r = 0;
        for (int c2 = 0; c2 < ncand; ++c2) {
            double v2 = cvd[c2];
            if (v2 > v || (v2 == v && cj[c2] < jj)) ++r;
        }
        if (r >= 1 && r < 63) {
            topvd[(size_t)i * K62 + r - 1] = v;
            topi[(size_t)i * K62 + r - 1] = jj;
        }
    }
}

// ---------------- encoded distances + ratio partial (atomic-free tail) ----------------
__global__ __launch_bounds__(256) void k_ratio(const double* __restrict__ Enc, const double* __restrict__ esqd,
                                               const double* __restrict__ topvd, const int* __restrict__ topi,
                                               double* __restrict__ vencd, double* __restrict__ Sp) {
    __shared__ double wp[4];
    int r = blockIdx.x * 4 + (threadIdx.x >> 6);
    int lane = threadIdx.x & 63, w = threadIdx.x >> 6;
    double ratio = 0.0;
    if (lane < K62) {
        int j = topi[(size_t)r * K62 + lane];
        const double* Er = Enc + (size_t)r * 16;
        const double* Ej = Enc + (size_t)j * 16;
        double dot = 0.0;
        #pragma unroll
        for (int q = 0; q < 16; ++q) dot = fma(Er[q], Ej[q], dot);
        double ve = sqrt(fmax(esqd[r] + esqd[j] - 2.0 * dot, 1e-12));
        vencd[(size_t)r * K62 + lane] = ve;
        ratio = topvd[(size_t)r * K62 + lane] / ve;
    }
    for (int o = 32; o > 0; o >>= 1) ratio += __shfl_down(ratio, o);
    if (lane == 0) wp[w] = ratio;
    __syncthreads();
    if (threadIdx.x == 0) Sp[blockIdx.x] = wp[0] + wp[1] + wp[2] + wp[3];
}

__global__ __launch_bounds__(256) void k_rsum(const double* __restrict__ Sp, double* __restrict__ Ssum) {
    __shared__ double wp[4];
    int t = threadIdx.x, lane = t & 63, w = t >> 6;
    double s = Sp[t] + Sp[t + 256] + Sp[t + 512] + Sp[t + 768];
    for (int o = 32; o > 0; o >>= 1) s += __shfl_down(s, o);
    if (lane == 0) wp[w] = s;
    __syncthreads();
    if (t == 0) Ssum[0] = wp[0] + wp[1] + wp[2] + wp[3];
}

__global__ __launch_bounds__(256) void k_loss(const double* __restrict__ topvd, const double* __restrict__ vencd,
                                              const double* __restrict__ Ssum, double* __restrict__ Lp) {
    __shared__ double wp[4];
    int r = blockIdx.x * 4 + (threadIdx.x >> 6);
    int lane = threadIdx.x & 63, w = threadIdx.x >> 6;
    double m = Ssum[0] * (1.0 / (4096.0 * 62.0));
    double v = -1.0;
    if (lane < K62) {
        double d = topvd[(size_t)r * K62 + lane] - m * vencd[(size_t)r * K62 + lane];
        v = d * d;
    }
    for (int o = 32; o > 0; o >>= 1) { double ov = __shfl_down(v, o); v = (ov > v) ? ov : v; }
    if (lane == 0) wp[w] = v;
    __syncthreads();
    if (threadIdx.x == 0) Lp[blockIdx.x] = wp[0] + wp[1] + wp[2] + wp[3];
}

__global__ __launch_bounds__(256) void k_final(const double* __restrict__ Lp, float* __restrict__ out) {
    __shared__ double wp[4];
    int t = threadIdx.x, lane = t & 63, w = t >> 6;
    double s = Lp[t] + Lp[t + 256] + Lp[t + 512] + Lp[t + 768];
    for (int o = 32; o > 0; o >>= 1) s += __shfl_down(s, o);
    if (lane == 0) wp[w] = s;
    __syncthreads();
    if (t == 0) out[0] = (float)((wp[0] + wp[1] + wp[2] + wp[3]) * (1.0 / 4096.0));
}

extern "C" void kernel_launch(void* const* d_in, const int* in_sizes, int n_in,
                              void* d_out, int out_size, void* d_ws, size_t ws_size,
                              hipStream_t stream) {
    const float* x   = (const float*)d_in[0];
    const float* cw1 = (const float*)d_in[1];
    const float* cb1 = (const float*)d_in[2];
    const float* cw2 = (const float*)d_in[3];
    const float* cb2 = (const float*)d_in[4];
    const float* cw3 = (const float*)d_in[5];
    const float* cb3 = (const float*)d_in[6];
    const float* dw  = (const float*)d_in[7];
    const float* db  = (const float*)d_in[8];

    char* wsb = (char*)d_ws;
    unsigned short* Dm16 = (unsigned short*)wsb;           // 4096*4096*2 = 33,554,432 B
    double* Enc   = (double*)(wsb + 33554432);             // 65,536 d = 524,288 B
    double* esqd  = (double*)(wsb + 34078720);             // 4,096 d
    double* sqnd  = (double*)(wsb + 34111488);             // 4,096 d
    float*  sqnf  = (float*)(wsb + 34144256);              // 4,096 f
    double* topvd = (double*)(wsb + 34160640);             // 253,952 d
    double* vencd = (double*)(wsb + 36192256);             // 253,952 d
    int*    topi  = (int*)(wsb + 38223872);                // 253,952 i
    double* Sp    = (double*)(wsb + 39239680);             // 1,024 d
    double* Lp    = (double*)(wsb + 39247872);             // 1,024 d
    double* Ssum  = (double*)(wsb + 39256064);             // 1 d
    float*  out   = (float*)d_out;

    k_sqnorm<<<1024, 256, 0, stream>>>(x, sqnd, sqnf);
    k_encgram<<<4624, 256, 0, stream>>>(x, cw1, cb1, cw2, cb2, cw3, cb3, dw, db,
                                        sqnf, Dm16, Enc, esqd);
    k_topsel<<<4096, 256, 0, stream>>>(Dm16, sqnd, x, topvd, topi);
    k_ratio<<<1024, 256, 0, stream>>>(Enc, esqd, topvd, topi, vencd, Sp);
    k_rsum<<<1, 256, 0, stream>>>(Sp, Ssum);
    k_loss<<<1024, 256, 0, stream>>>(topvd, vencd, Ssum, Lp);
    k_final<<<1, 256, 0, stream>>>(Lp, out);
}